// Round 1
// baseline (633.556 us; speedup 1.0000x reference)
//
#include <hip/hip_runtime.h>

#define HID 1024
#define SEQ 2048
#define NB  16

typedef __attribute__((ext_vector_type(8))) short bf16x8;
typedef __attribute__((ext_vector_type(4))) float f32x4;

static __device__ __forceinline__ short f2bf(float f) {
    union { float f; unsigned u; } v; v.f = f;
    unsigned u = v.u + 0x7fffu + ((v.u >> 16) & 1u);   // round-to-nearest-even
    return (short)(u >> 16);
}
static __device__ __forceinline__ unsigned pk2(float a, float b) {
    return (unsigned)(unsigned short)f2bf(a) | ((unsigned)(unsigned short)f2bf(b) << 16);
}

// ---- prep: qproj (atomic f-split) + w1t transpose. Keys conversion REMOVED
// (the score kernel now reads keys fp32 directly, exactly once).
//   [0,32)      qproj
//   [32,1056)   w1t[n][k] = bf16(W1[H+k][n])
__global__ __launch_bounds__(256) void prep_all(const float* __restrict__ W1,
                                                const float* __restrict__ queries,
                                                const float* __restrict__ b1,
                                                short* __restrict__ w1t,
                                                float* __restrict__ qproj) {
    __shared__ float shmem[2048];          // 8 KB, aliased per section
    const int tid = threadIdx.x;
    int bw = blockIdx.x;

    if (bw < 32) {  // qproj[b][n] += b1 + sum_f q[b][f]*W1[f][n], f-chunk 128, n-chunk 256
        const int f0 = (bw >> 2) * 128;
        const int n0 = (bw & 3) * 256;
#pragma unroll
        for (int j = 0; j < 8; ++j) {
            const int idx = tid * 8 + j;
            const int b = idx >> 7, f = idx & 127;
            shmem[idx] = queries[b * HID + f0 + f];
        }
        __syncthreads();
        float acc[16];
        const float bv = (bw >> 2 == 0) ? b1[n0 + tid] : 0.0f;
#pragma unroll
        for (int b = 0; b < 16; ++b) acc[b] = bv;
        for (int f = 0; f < 128; ++f) {
            const float w = W1[(size_t)(f0 + f) * HID + n0 + tid];
#pragma unroll
            for (int b = 0; b < 16; ++b)
                acc[b] += shmem[b * 128 + f] * w;
        }
#pragma unroll
        for (int b = 0; b < 16; ++b)
            atomicAdd(&qproj[b * HID + n0 + tid], acc[b]);
        return;
    }
    bw -= 32;
    {  // w1t transpose, 32x32 tiles
        float (*t)[33] = (float(*)[33])shmem;   // 32x33 floats
        const int k0 = (bw & 31) * 32;
        const int n0 = (bw >> 5) * 32;
        const int tx = tid & 31, ty = tid >> 5;
#pragma unroll
        for (int i = 0; i < 32; i += 8)
            t[ty + i][tx] = W1[(size_t)(HID + k0 + ty + i) * HID + n0 + tx];
        __syncthreads();
#pragma unroll
        for (int i = 0; i < 32; i += 8)
            w1t[(size_t)(n0 + ty + i) * HID + k0 + tx] = f2bf(t[tx][ty + i]);
    }
}

// ---- fused score kernel: m-tile 64, full-N per block.
// A (keys, fp32) staged ONCE into LDS as swizzled bf16 (128 KiB).
// 8 waves, each owns a private 128-wide n-slice; B fragments come straight
// from w1t (L2-resident, 2 MB) into registers -> NO barriers in the K loop.
// Epilogue: relu(acc+qproj)*W2, reduce n across lanes + waves, direct store
// of final scores (no atomics, no pre-zeroing).
__global__ __launch_bounds__(512, 2) void score_fused(const float* __restrict__ keys,
                                                      const short* __restrict__ w1t,
                                                      const float* __restrict__ qproj,
                                                      const float* __restrict__ W2,
                                                      float* __restrict__ scores) {
    __shared__ __align__(16) short A[64 * HID];   // 128 KiB, 16B-slot XOR swizzle per row
    __shared__ float red[8][64];

    const int tid  = threadIdx.x;
    const int lane = tid & 63;
    const int wave = tid >> 6;
    const int c = lane & 15, q = lane >> 4;
    const int m0 = blockIdx.x * 64;
    const int batch = m0 >> 11;                   // 32 blocks per batch (64*32 = 2048)

    // ---- stage A: keys[m0:m0+64][0:1024] fp32 -> bf16 LDS, swizzled ----
    // slot = 8 consecutive bf16 (16 B). dest slot = slot ^ (row & 7).
#pragma unroll
    for (int it = 0; it < 16; ++it) {
        const int idx  = it * 512 + tid;          // 8192 slots total
        const int row  = idx >> 7;
        const int slot = idx & 127;
        const float* src = keys + (size_t)(m0 + row) * HID + slot * 8;
        const float4 v0 = *(const float4*)src;
        const float4 v1 = *(const float4*)(src + 4);
        int4 o;
        o.x = (int)pk2(v0.x, v0.y); o.y = (int)pk2(v0.z, v0.w);
        o.z = (int)pk2(v1.x, v1.y); o.w = (int)pk2(v1.z, v1.w);
        *(int4*)&A[row * HID + ((slot ^ (row & 7)) << 3)] = o;
    }
    __syncthreads();

    const int xr = c & 7;                          // row = mi*16 + c -> row&7 == c&7
    float psum[4][4] = {};

#pragma unroll 1
    for (int g = 0; g < 2; ++g) {                  // two 64-wide n-groups per wave
        const int nb = wave * 128 + g * 64;
        f32x4 acc[4][4] = {};
        // B base: row nb+ni*16+c, k offset q*8
        const short* b0 = w1t + (size_t)(nb + c) * HID + q * 8;
#pragma unroll
        for (int k0 = 0; k0 < HID; k0 += 32) {
            bf16x8 bf[4], af[4];
#pragma unroll
            for (int ni = 0; ni < 4; ++ni)
                bf[ni] = *(const bf16x8*)(b0 + ni * 16 * HID + k0);
#pragma unroll
            for (int mi = 0; mi < 4; ++mi)
                af[mi] = *(const bf16x8*)&A[(mi * 16 + c) * HID + ((((k0 >> 3) + q) ^ xr) << 3)];
#pragma unroll
            for (int mi = 0; mi < 4; ++mi)
#pragma unroll
                for (int ni = 0; ni < 4; ++ni)
                    acc[mi][ni] = __builtin_amdgcn_mfma_f32_16x16x32_bf16(af[mi], bf[ni], acc[mi][ni], 0, 0, 0);
        }
        // fold this n-group: relu(acc + qproj) * W2, accumulate per m-row
#pragma unroll
        for (int ni = 0; ni < 4; ++ni) {
            const int n = nb + ni * 16 + c;
            const float qv = qproj[batch * HID + n];
            const float wv = W2[n];
#pragma unroll
            for (int mi = 0; mi < 4; ++mi)
#pragma unroll
                for (int r = 0; r < 4; ++r)
                    psum[mi][r] += fmaxf(acc[mi][ni][r] + qv, 0.f) * wv;
        }
    }

    // reduce over the 16 c-lanes (n-dimension); q-lanes index m-rows
#pragma unroll
    for (int m = 1; m < 16; m <<= 1)
#pragma unroll
        for (int mi = 0; mi < 4; ++mi)
#pragma unroll
            for (int r = 0; r < 4; ++r)
                psum[mi][r] += __shfl_xor(psum[mi][r], m, 64);
    if (c == 0) {
#pragma unroll
        for (int mi = 0; mi < 4; ++mi)
#pragma unroll
            for (int r = 0; r < 4; ++r)
                red[wave][mi * 16 + q * 4 + r] = psum[mi][r];
    }
    __syncthreads();
    if (tid < 64) {  // sum the 8 waves' disjoint n-slices -> final scores
        float s = 0.f;
#pragma unroll
        for (int w = 0; w < 8; ++w) s += red[w][tid];
        scores[m0 + tid] = s;
    }
}

// ---- softmax over S per batch -> alphas; also zero context accumulator ----
__global__ __launch_bounds__(256) void softmax_k(const float* __restrict__ scores,
                                                 float* __restrict__ alphas,
                                                 float* __restrict__ ctx) {
    __shared__ float red[256];
    const int b = blockIdx.x;
    const int tid = threadIdx.x;
    float4 z = {0.f, 0.f, 0.f, 0.f};
    *(float4*)(ctx + b * HID + tid * 4) = z;

    float loc[8];
    float mx = -1e30f;
#pragma unroll
    for (int i = 0; i < 8; ++i) {
        loc[i] = scores[b * SEQ + tid + i * 256];
        mx = fmaxf(mx, loc[i]);
    }
    red[tid] = mx; __syncthreads();
    for (int s = 128; s > 0; s >>= 1) {
        if (tid < s) red[tid] = fmaxf(red[tid], red[tid + s]);
        __syncthreads();
    }
    mx = red[0]; __syncthreads();
    float sum = 0.f;
#pragma unroll
    for (int i = 0; i < 8; ++i) { loc[i] = expf(loc[i] - mx); sum += loc[i]; }
    red[tid] = sum; __syncthreads();
    for (int s = 128; s > 0; s >>= 1) {
        if (tid < s) red[tid] += red[tid + s];
        __syncthreads();
    }
    const float inv = 1.0f / red[0];
#pragma unroll
    for (int i = 0; i < 8; ++i) alphas[b * SEQ + tid + i * 256] = loc[i] * inv;
}

// ---- context[b][h] = sum_s alphas[b][s] * values[b][s][h] (s split 32-way, atomics) ----
__global__ __launch_bounds__(256) void context_k(const float* __restrict__ alphas,
                                                 const float* __restrict__ values,
                                                 float* __restrict__ context) {
    __shared__ float al[64];
    const int b = blockIdx.y;
    const int s0 = blockIdx.x * 64;
    const int tid = threadIdx.x;
    if (tid < 64) al[tid] = alphas[b * SEQ + s0 + tid];
    __syncthreads();
    const int col = tid * 4;
    float4 acc = {0.f, 0.f, 0.f, 0.f};
#pragma unroll 4
    for (int i = 0; i < 64; ++i) {
        const float a = al[i];
        const float4 v = *(const float4*)(values + (size_t)(b * SEQ + s0 + i) * HID + col);
        acc.x += a * v.x; acc.y += a * v.y; acc.z += a * v.z; acc.w += a * v.w;
    }
    float* cp = context + b * HID + col;
    atomicAdd(cp + 0, acc.x);
    atomicAdd(cp + 1, acc.y);
    atomicAdd(cp + 2, acc.z);
    atomicAdd(cp + 3, acc.w);
}

extern "C" void kernel_launch(void* const* d_in, const int* in_sizes, int n_in,
                              void* d_out, int out_size, void* d_ws, size_t ws_size,
                              hipStream_t stream) {
    const float* queries = (const float*)d_in[0];
    const float* keys    = (const float*)d_in[1];
    const float* values  = (const float*)d_in[2];
    const float* W1      = (const float*)d_in[3];
    const float* b1      = (const float*)d_in[4];
    const float* W2      = (const float*)d_in[5];
    // d_in[6] = b2: softmax is shift-invariant; b2 affects neither alphas nor context.

    float* out_ctx   = (float*)d_out;            // [16,1024]
    float* out_alpha = (float*)d_out + NB * HID; // [16,2048]

    char* ws = (char*)d_ws;
    float* scores = (float*)ws;                       // 131072 B (written fully, no memset)
    float* qproj  = (float*)(ws + 131072);            // 65536 B (atomic target)
    short* w1t    = (short*)(ws + 196608);            // 2 MiB

    hipMemsetAsync(ws + 131072, 0, 65536, stream);    // qproj only

    prep_all<<<32 + 1024, 256, 0, stream>>>(W1, queries, b1, w1t, qproj);

    score_fused<<<512, 512, 0, stream>>>(keys, w1t, qproj, W2, scores);

    softmax_k<<<NB, 256, 0, stream>>>(scores, out_alpha, out_ctx);
    context_k<<<dim3(32, NB), 256, 0, stream>>>(out_alpha, values, out_ctx);
}

// Round 2
// 431.268 us; speedup vs baseline: 1.4691x; 1.4691x over previous
//
#include <hip/hip_runtime.h>

#define HID 1024
#define SEQ 2048
#define NB  16

typedef __attribute__((ext_vector_type(8))) short bf16x8;
typedef __attribute__((ext_vector_type(4))) float f32x4;

static __device__ __forceinline__ short f2bf(float f) {
    union { float f; unsigned u; } v; v.f = f;
    unsigned u = v.u + 0x7fffu + ((v.u >> 16) & 1u);   // round-to-nearest-even
    return (short)(u >> 16);
}
static __device__ __forceinline__ unsigned pk2(float a, float b) {
    return (unsigned)(unsigned short)f2bf(a) | ((unsigned)(unsigned short)f2bf(b) << 16);
}
// async global->LDS, 16B per lane. LDS dest = wave-uniform base + lane*16.
static __device__ __forceinline__ void glds16(const void* g, void* l) {
    __builtin_amdgcn_global_load_lds(
        (const __attribute__((address_space(1))) unsigned*)g,
        (__attribute__((address_space(3))) unsigned*)l, 16, 0, 0);
}

// ---- prep: qproj (atomic f-split) + w1t transpose. NO keys conversion —
// the score kernel reads keys fp32 directly (exactly once from HBM, thanks
// to the sibling-grouped XCD swizzle + L2 reuse).
//   [0,32)      qproj
//   [32,1056)   w1t[n][k] = bf16(W1[H+k][n])
__global__ __launch_bounds__(256) void prep_all(const float* __restrict__ W1,
                                                const float* __restrict__ queries,
                                                const float* __restrict__ b1,
                                                short* __restrict__ w1t,
                                                float* __restrict__ qproj) {
    __shared__ float shmem[2048];          // 8 KB, aliased per section
    const int tid = threadIdx.x;
    int bw = blockIdx.x;

    if (bw < 32) {  // qproj[b][n] += b1 + sum_f q[b][f]*W1[f][n], f-chunk 128, n-chunk 256
        const int f0 = (bw >> 2) * 128;
        const int n0 = (bw & 3) * 256;
#pragma unroll
        for (int j = 0; j < 8; ++j) {
            const int idx = tid * 8 + j;
            const int b = idx >> 7, f = idx & 127;
            shmem[idx] = queries[b * HID + f0 + f];
        }
        __syncthreads();
        float acc[16];
        const float bv = (bw >> 2 == 0) ? b1[n0 + tid] : 0.0f;
#pragma unroll
        for (int b = 0; b < 16; ++b) acc[b] = bv;
        for (int f = 0; f < 128; ++f) {
            const float w = W1[(size_t)(f0 + f) * HID + n0 + tid];
#pragma unroll
            for (int b = 0; b < 16; ++b)
                acc[b] += shmem[b * 128 + f] * w;
        }
#pragma unroll
        for (int b = 0; b < 16; ++b)
            atomicAdd(&qproj[b * HID + n0 + tid], acc[b]);
        return;
    }
    bw -= 32;
    {  // w1t transpose, 32x32 tiles
        float (*t)[33] = (float(*)[33])shmem;   // 32x33 floats
        const int k0 = (bw & 31) * 32;
        const int n0 = (bw >> 5) * 32;
        const int tx = tid & 31, ty = tid >> 5;
#pragma unroll
        for (int i = 0; i < 32; i += 8)
            t[ty + i][tx] = W1[(size_t)(HID + k0 + ty + i) * HID + n0 + tx];
        __syncthreads();
#pragma unroll
        for (int i = 0; i < 32; i += 8)
            w1t[(size_t)(n0 + ty + i) * HID + k0 + tx] = f2bf(t[tx][ty + i]);
    }
}

// ---- main fused score GEMM: 128x128 tile, BK=32, 4 waves (2x2), 4x4 frags/wave.
// scores[m] += sum_n relu(keys[m]·W1bot[:,n] + qproj[b][n]) * W2[n]
//
// Block mapping (sibling-grouped XCD swizzle): the 8 n-blocks sharing one
// A-panel (same m) get linear ids {x, x+8, ..., x+56} -> same id%8 -> same
// XCD -> the keys panel is HBM-fetched once, L2-serves the other 7.
//   n_blk = (id>>3)&7,  m_blk = (id>>6)*8 + (id&7)
//
// LDS bank-conflict XOR swizzle (slot = 16B unit, 4 slots/row):
//   stored slot = logical slot ^ (row&3); for B this is applied by permuting
//   the glds *source* k-chunk per lane (LDS dest must stay linear), for A by
//   permuting the ds_write address. Fragment reads use slot q ^ (c&3).
__global__ __launch_bounds__(256) void score_gemm(const float* __restrict__ keys,
                                                  const short* __restrict__ w1t,
                                                  const float* __restrict__ qproj,
                                                  const float* __restrict__ W2,
                                                  float* __restrict__ scores) {
    __shared__ short As[128 * 32];  // [m][k-chunk] bf16, XOR-swizzled slots
    __shared__ short Bs[128 * 32];  // [n][k-chunk] bf16, XOR-swizzled slots

    const int tid  = threadIdx.x;
    const int lane = tid & 63;
    const int wave = tid >> 6;
    const int id   = blockIdx.x;
    const int n_blk = (id >> 3) & 7;
    const int m_blk = (id >> 6) * 8 + (id & 7);
    const int n0 = n_blk * 128;
    const int m0 = m_blk * 128;
    const int batch = m0 >> 11;
    const int wm = wave >> 1, wn = wave & 1;   // wave quadrant
    const int q = lane >> 4, c = lane & 15;
    const int xr = c & 3;                      // fragment row & 3

    // glds per-call lane mapping: row = rbase + lane/4, source k-chunk
    // pre-swizzled so linear LDS dest receives the swizzled layout.
    const int lrow = lane >> 2;
    const int lk   = ((lane & 3) ^ (lrow & 3)) << 3;

    // A conversion mapping: thread t -> row t>>1, half (t&1)*16 (16 floats)
    const int ar  = tid >> 1;
    const int ah  = (tid & 1) * 16;
    const int as0 = (((ah >> 3) + 0) ^ (ar & 3)) << 3;   // swizzled dest slots
    const int as1 = (((ah >> 3) + 1) ^ (ar & 3)) << 3;
    const float* asrc = keys + (size_t)(m0 + ar) * HID + ah;

    f32x4 acc[4][4] = {};

    for (int k0 = 0; k0 < HID; k0 += 32) {
        // B: 8 KB via 2 glds calls per wave (source-swizzled)
#pragma unroll
        for (int call = 0; call < 2; ++call) {
            const int rbase = (wave * 2 + call) * 16;
            glds16(w1t + (size_t)(n0 + rbase + lrow) * HID + k0 + lk,
                   &Bs[rbase * 32]);
        }
        // A: convert fp32->bf16 in-register, swizzled ds_write
        {
            const float4 v0 = *(const float4*)(asrc + k0 + 0);
            const float4 v1 = *(const float4*)(asrc + k0 + 4);
            const float4 v2 = *(const float4*)(asrc + k0 + 8);
            const float4 v3 = *(const float4*)(asrc + k0 + 12);
            int4 o0, o1;
            o0.x = (int)pk2(v0.x, v0.y); o0.y = (int)pk2(v0.z, v0.w);
            o0.z = (int)pk2(v1.x, v1.y); o0.w = (int)pk2(v1.z, v1.w);
            o1.x = (int)pk2(v2.x, v2.y); o1.y = (int)pk2(v2.z, v2.w);
            o1.z = (int)pk2(v3.x, v3.y); o1.w = (int)pk2(v3.z, v3.w);
            *(int4*)&As[ar * 32 + as0] = o0;
            *(int4*)&As[ar * 32 + as1] = o1;
        }
        __syncthreads();

        bf16x8 af[4], bf[4];
#pragma unroll
        for (int i = 0; i < 4; ++i)
            af[i] = *(const bf16x8*)&As[(wm * 64 + i * 16 + c) * 32 + ((q ^ xr) << 3)];
#pragma unroll
        for (int i = 0; i < 4; ++i)
            bf[i] = *(const bf16x8*)&Bs[(wn * 64 + i * 16 + c) * 32 + ((q ^ xr) << 3)];
#pragma unroll
        for (int mi = 0; mi < 4; ++mi)
#pragma unroll
            for (int ni = 0; ni < 4; ++ni)
                acc[mi][ni] = __builtin_amdgcn_mfma_f32_16x16x32_bf16(af[mi], bf[ni], acc[mi][ni], 0, 0, 0);
        __syncthreads();
    }

    // epilogue: relu(acc + qproj) * W2, reduce over this wave's 64 n-cols
    const float* qp = qproj + batch * HID + n0 + wn * 64;
    const float* w2 = W2 + n0 + wn * 64;
    float psum[4][4] = {};
#pragma unroll
    for (int ni = 0; ni < 4; ++ni) {
        const float qv = qp[ni * 16 + c];
        const float wv = w2[ni * 16 + c];
#pragma unroll
        for (int mi = 0; mi < 4; ++mi)
#pragma unroll
            for (int r = 0; r < 4; ++r)
                psum[mi][r] += fmaxf(acc[mi][ni][r] + qv, 0.f) * wv;
    }
#pragma unroll
    for (int m = 1; m < 16; m <<= 1)
#pragma unroll
        for (int mi = 0; mi < 4; ++mi)
#pragma unroll
            for (int r = 0; r < 4; ++r)
                psum[mi][r] += __shfl_xor(psum[mi][r], m, 64);
    if (c == 0) {
#pragma unroll
        for (int mi = 0; mi < 4; ++mi) {
            const int row = m0 + wm * 64 + mi * 16 + q * 4;
#pragma unroll
            for (int r = 0; r < 4; ++r)
                atomicAdd(&scores[row + r], psum[mi][r]);
        }
    }
}

// ---- softmax over S per batch -> alphas; also zero context accumulator ----
__global__ __launch_bounds__(256) void softmax_k(const float* __restrict__ scores,
                                                 float* __restrict__ alphas,
                                                 float* __restrict__ ctx) {
    __shared__ float red[256];
    const int b = blockIdx.x;
    const int tid = threadIdx.x;
    float4 z = {0.f, 0.f, 0.f, 0.f};
    *(float4*)(ctx + b * HID + tid * 4) = z;

    float loc[8];
    float mx = -1e30f;
#pragma unroll
    for (int i = 0; i < 8; ++i) {
        loc[i] = scores[b * SEQ + tid + i * 256];
        mx = fmaxf(mx, loc[i]);
    }
    red[tid] = mx; __syncthreads();
    for (int s = 128; s > 0; s >>= 1) {
        if (tid < s) red[tid] = fmaxf(red[tid], red[tid + s]);
        __syncthreads();
    }
    mx = red[0]; __syncthreads();
    float sum = 0.f;
#pragma unroll
    for (int i = 0; i < 8; ++i) { loc[i] = expf(loc[i] - mx); sum += loc[i]; }
    red[tid] = sum; __syncthreads();
    for (int s = 128; s > 0; s >>= 1) {
        if (tid < s) red[tid] += red[tid + s];
        __syncthreads();
    }
    const float inv = 1.0f / red[0];
#pragma unroll
    for (int i = 0; i < 8; ++i) alphas[b * SEQ + tid + i * 256] = loc[i] * inv;
}

// ---- context[b][h] = sum_s alphas[b][s] * values[b][s][h] (s split 32-way, atomics) ----
__global__ __launch_bounds__(256) void context_k(const float* __restrict__ alphas,
                                                 const float* __restrict__ values,
                                                 float* __restrict__ context) {
    __shared__ float al[64];
    const int b = blockIdx.y;
    const int s0 = blockIdx.x * 64;
    const int tid = threadIdx.x;
    if (tid < 64) al[tid] = alphas[b * SEQ + s0 + tid];
    __syncthreads();
    const int col = tid * 4;
    float4 acc = {0.f, 0.f, 0.f, 0.f};
#pragma unroll 4
    for (int i = 0; i < 64; ++i) {
        const float a = al[i];
        const float4 v = *(const float4*)(values + (size_t)(b * SEQ + s0 + i) * HID + col);
        acc.x += a * v.x; acc.y += a * v.y; acc.z += a * v.z; acc.w += a * v.w;
    }
    float* cp = context + b * HID + col;
    atomicAdd(cp + 0, acc.x);
    atomicAdd(cp + 1, acc.y);
    atomicAdd(cp + 2, acc.z);
    atomicAdd(cp + 3, acc.w);
}

extern "C" void kernel_launch(void* const* d_in, const int* in_sizes, int n_in,
                              void* d_out, int out_size, void* d_ws, size_t ws_size,
                              hipStream_t stream) {
    const float* queries = (const float*)d_in[0];
    const float* keys    = (const float*)d_in[1];
    const float* values  = (const float*)d_in[2];
    const float* W1      = (const float*)d_in[3];
    const float* b1      = (const float*)d_in[4];
    const float* W2      = (const float*)d_in[5];
    // d_in[6] = b2: softmax is shift-invariant; b2 affects neither alphas nor context.

    float* out_ctx   = (float*)d_out;            // [16,1024]
    float* out_alpha = (float*)d_out + NB * HID; // [16,2048]

    char* ws = (char*)d_ws;
    float* scores = (float*)ws;                       // 131072 B (atomic target)
    float* qproj  = (float*)(ws + 131072);            // 65536 B (atomic target)
    short* w1t    = (short*)(ws + 196608);            // 2 MiB

    hipMemsetAsync(ws, 0, 196608, stream);            // scores + qproj

    prep_all<<<32 + 1024, 256, 0, stream>>>(W1, queries, b1, w1t, qproj);

    score_gemm<<<2048, 256, 0, stream>>>(keys, w1t, qproj, W2, scores);

    softmax_k<<<NB, 256, 0, stream>>>(scores, out_alpha, out_ctx);
    context_k<<<dim3(32, NB), 256, 0, stream>>>(out_alpha, values, out_ctx);
}

// Round 4
// 411.639 us; speedup vs baseline: 1.5391x; 1.0477x over previous
//
#include <hip/hip_runtime.h>

#define HID 1024
#define SEQ 2048
#define NB  16

typedef __attribute__((ext_vector_type(8))) short bf16x8;
typedef __attribute__((ext_vector_type(4))) float f32x4;

static __device__ __forceinline__ short f2bf(float f) {
    union { float f; unsigned u; } v; v.f = f;
    unsigned u = v.u + 0x7fffu + ((v.u >> 16) & 1u);   // round-to-nearest-even
    return (short)(u >> 16);
}
// HW-packed fp32x2 -> bf16x2 via v_cvt_pk_bf16_f32 (no builtin on gfx950 — inline asm)
static __device__ __forceinline__ unsigned pk2h(float a, float b) {
    unsigned r;
    asm("v_cvt_pk_bf16_f32 %0, %1, %2" : "=v"(r) : "v"(a), "v"(b));
    return r;
}
// async global->LDS, 16B per lane. LDS dest = wave-uniform base + lane*16.
static __device__ __forceinline__ void glds16(const void* g, void* l) {
    __builtin_amdgcn_global_load_lds(
        (const __attribute__((address_space(1))) unsigned*)g,
        (__attribute__((address_space(3))) unsigned*)l, 16, 0, 0);
}

// ---- prep: qproj (atomic f-split) + w1t transpose (linear [n][k] layout).
__global__ __launch_bounds__(256) void prep_all(const float* __restrict__ W1,
                                                const float* __restrict__ queries,
                                                const float* __restrict__ b1,
                                                short* __restrict__ w1t,
                                                float* __restrict__ qproj) {
    __shared__ float shmem[2048];          // 8 KB, aliased per section
    const int tid = threadIdx.x;
    int bw = blockIdx.x;

    if (bw < 32) {  // qproj[b][n] += b1 + sum_f q[b][f]*W1[f][n], f-chunk 128, n-chunk 256
        const int f0 = (bw >> 2) * 128;
        const int n0 = (bw & 3) * 256;
#pragma unroll
        for (int j = 0; j < 8; ++j) {
            const int idx = tid * 8 + j;
            const int b = idx >> 7, f = idx & 127;
            shmem[idx] = queries[b * HID + f0 + f];
        }
        __syncthreads();
        float acc[16];
        const float bv = (bw >> 2 == 0) ? b1[n0 + tid] : 0.0f;
#pragma unroll
        for (int b = 0; b < 16; ++b) acc[b] = bv;
        for (int f = 0; f < 128; ++f) {
            const float w = W1[(size_t)(f0 + f) * HID + n0 + tid];
#pragma unroll
            for (int b = 0; b < 16; ++b)
                acc[b] += shmem[b * 128 + f] * w;
        }
#pragma unroll
        for (int b = 0; b < 16; ++b)
            atomicAdd(&qproj[b * HID + n0 + tid], acc[b]);
        return;
    }
    bw -= 32;
    {  // w1t transpose, 32x32 tiles
        float (*t)[33] = (float(*)[33])shmem;   // 32x33 floats
        const int k0 = (bw & 31) * 32;
        const int n0 = (bw >> 5) * 32;
        const int tx = tid & 31, ty = tid >> 5;
#pragma unroll
        for (int i = 0; i < 32; i += 8)
            t[ty + i][tx] = W1[(size_t)(HID + k0 + ty + i) * HID + n0 + tx];
        __syncthreads();
#pragma unroll
        for (int i = 0; i < 32; i += 8)
            w1t[(size_t)(n0 + ty + i) * HID + k0 + tx] = f2bf(t[tx][ty + i]);
    }
}

// ---- main fused score GEMM: 128x128 tile, BK=32, 4 waves (2x2), 4x4 frags/wave.
// scores[m] += sum_n relu(keys[m]·W1bot[:,n] + qproj[b][n]) * W2[n]
//
// XCD sibling swizzle: 8 n-blocks sharing an A-panel -> same id%8 -> same XCD
// (keys panel HBM-fetched once, L2 serves the other 7; w1t 2MB L2-resident).
//
// LDS XOR swizzle (slot = 16B unit, 4/row, row stride 64B): phys = s ^ ((row>>1)&3)
// -> bank group (4*row + phys) mod 8 hits each group exactly 2x per 16 lanes (free).
// Applied: B via glds SOURCE k-permute (LDS dest linear), A via ds_write addr,
// reads via slot q ^ ((c>>1)&3).
//
// Software pipeline (double-buffered As/Bs, one barrier/iter):
//   iter t: glds Bs[nxt]<-B(t+1); cvt regs(t+1)+ds_write As[nxt]; load keys(t+2);
//           ds_read+16 MFMA from [cur]; __syncthreads.
__global__ __launch_bounds__(256, 4) void score_gemm(const float* __restrict__ keys,
                                                     const short* __restrict__ w1t,
                                                     const float* __restrict__ qproj,
                                                     const float* __restrict__ W2,
                                                     float* __restrict__ scores) {
    __shared__ short As[2][128 * 32];
    __shared__ short Bs[2][128 * 32];

    const int tid  = threadIdx.x;
    const int lane = tid & 63;
    const int wave = tid >> 6;
    const int id   = blockIdx.x;
    const int n_blk = (id >> 3) & 7;
    const int m_blk = (id >> 6) * 8 + (id & 7);
    const int n0 = n_blk * 128;
    const int m0 = m_blk * 128;
    const int batch = m0 >> 11;
    const int wm = wave >> 1, wn = wave & 1;
    const int q = lane >> 4, c = lane & 15;
    const int xr = (c >> 1) & 3;               // read-side XOR

    // B glds mapping: row = rbase + lane/4, source k-chunk pre-permuted so the
    // linear LDS dest receives phys = s ^ ((row>>1)&3); row>>1 bits = lane>>3.
    const int lrow = lane >> 2;
    const int lk   = ((lane & 3) ^ ((lane >> 3) & 3)) << 3;
    const short* bsrc = w1t + (size_t)(n0 + lrow) * HID + lk;

    // A conversion mapping: thread t -> row t>>1, half (t&1)*16 (16 floats)
    const int ar  = tid >> 1;
    const int ah  = (tid & 1) * 16;
    const int g_ar = (ar >> 1) & 3;
    const int as0 = (((ah >> 3) + 0) ^ g_ar) << 3;
    const int as1 = (((ah >> 3) + 1) ^ g_ar) << 3;
    const float* asrc = keys + (size_t)(m0 + ar) * HID + ah;

    f32x4 acc[4][4] = {};

    // ---- prologue: stage chunk 0, prefetch keys chunk 1 ----
    float4 ua0 = *(const float4*)(asrc + 0);
    float4 ua1 = *(const float4*)(asrc + 4);
    float4 ua2 = *(const float4*)(asrc + 8);
    float4 ua3 = *(const float4*)(asrc + 12);
#pragma unroll
    for (int call = 0; call < 2; ++call) {
        const int rbase = (wave * 2 + call) * 16;
        glds16(bsrc + (size_t)rbase * HID, &Bs[0][rbase * 32]);
    }
    {
        int4 o0, o1;
        o0.x = (int)pk2h(ua0.x, ua0.y); o0.y = (int)pk2h(ua0.z, ua0.w);
        o0.z = (int)pk2h(ua1.x, ua1.y); o0.w = (int)pk2h(ua1.z, ua1.w);
        o1.x = (int)pk2h(ua2.x, ua2.y); o1.y = (int)pk2h(ua2.z, ua2.w);
        o1.z = (int)pk2h(ua3.x, ua3.y); o1.w = (int)pk2h(ua3.z, ua3.w);
        *(int4*)&As[0][ar * 32 + as0] = o0;
        *(int4*)&As[0][ar * 32 + as1] = o1;
    }
    ua0 = *(const float4*)(asrc + 32);
    ua1 = *(const float4*)(asrc + 36);
    ua2 = *(const float4*)(asrc + 40);
    ua3 = *(const float4*)(asrc + 44);
    __syncthreads();

    for (int t = 0; t < 32; ++t) {
        const int cur = t & 1, nxt = cur ^ 1;
        if (t < 31) {
            const int k1 = (t + 1) * 32;
#pragma unroll
            for (int call = 0; call < 2; ++call) {
                const int rbase = (wave * 2 + call) * 16;
                glds16(bsrc + (size_t)rbase * HID + k1, &Bs[nxt][rbase * 32]);
            }
            int4 o0, o1;
            o0.x = (int)pk2h(ua0.x, ua0.y); o0.y = (int)pk2h(ua0.z, ua0.w);
            o0.z = (int)pk2h(ua1.x, ua1.y); o0.w = (int)pk2h(ua1.z, ua1.w);
            o1.x = (int)pk2h(ua2.x, ua2.y); o1.y = (int)pk2h(ua2.z, ua2.w);
            o1.z = (int)pk2h(ua3.x, ua3.y); o1.w = (int)pk2h(ua3.z, ua3.w);
            *(int4*)&As[nxt][ar * 32 + as0] = o0;
            *(int4*)&As[nxt][ar * 32 + as1] = o1;
            if (t < 30) {
                const float* s2 = asrc + (t + 2) * 32;
                ua0 = *(const float4*)(s2 + 0);
                ua1 = *(const float4*)(s2 + 4);
                ua2 = *(const float4*)(s2 + 8);
                ua3 = *(const float4*)(s2 + 12);
            }
        }
        bf16x8 af[4], bf[4];
#pragma unroll
        for (int i = 0; i < 4; ++i)
            af[i] = *(const bf16x8*)&As[cur][(wm * 64 + i * 16 + c) * 32 + ((q ^ xr) << 3)];
#pragma unroll
        for (int i = 0; i < 4; ++i)
            bf[i] = *(const bf16x8*)&Bs[cur][(wn * 64 + i * 16 + c) * 32 + ((q ^ xr) << 3)];
#pragma unroll
        for (int mi = 0; mi < 4; ++mi)
#pragma unroll
            for (int ni = 0; ni < 4; ++ni)
                acc[mi][ni] = __builtin_amdgcn_mfma_f32_16x16x32_bf16(af[mi], bf[ni], acc[mi][ni], 0, 0, 0);
        __syncthreads();
    }

    // epilogue: relu(acc + qproj) * W2, reduce over this wave's 64 n-cols
    const float* qp = qproj + batch * HID + n0 + wn * 64;
    const float* w2 = W2 + n0 + wn * 64;
    float psum[4][4] = {};
#pragma unroll
    for (int ni = 0; ni < 4; ++ni) {
        const float qv = qp[ni * 16 + c];
        const float wv = w2[ni * 16 + c];
#pragma unroll
        for (int mi = 0; mi < 4; ++mi)
#pragma unroll
            for (int r = 0; r < 4; ++r)
                psum[mi][r] += fmaxf(acc[mi][ni][r] + qv, 0.f) * wv;
    }
#pragma unroll
    for (int m = 1; m < 16; m <<= 1)
#pragma unroll
        for (int mi = 0; mi < 4; ++mi)
#pragma unroll
            for (int r = 0; r < 4; ++r)
                psum[mi][r] += __shfl_xor(psum[mi][r], m, 64);
    if (c == 0) {
#pragma unroll
        for (int mi = 0; mi < 4; ++mi) {
            const int row = m0 + wm * 64 + mi * 16 + q * 4;
#pragma unroll
            for (int r = 0; r < 4; ++r)
                atomicAdd(&scores[row + r], psum[mi][r]);
        }
    }
}

// ---- softmax over S per batch -> alphas; also zero context accumulator ----
__global__ __launch_bounds__(256) void softmax_k(const float* __restrict__ scores,
                                                 float* __restrict__ alphas,
                                                 float* __restrict__ ctx) {
    __shared__ float red[256];
    const int b = blockIdx.x;
    const int tid = threadIdx.x;
    float4 z = {0.f, 0.f, 0.f, 0.f};
    *(float4*)(ctx + b * HID + tid * 4) = z;

    float loc[8];
    float mx = -1e30f;
#pragma unroll
    for (int i = 0; i < 8; ++i) {
        loc[i] = scores[b * SEQ + tid + i * 256];
        mx = fmaxf(mx, loc[i]);
    }
    red[tid] = mx; __syncthreads();
    for (int s = 128; s > 0; s >>= 1) {
        if (tid < s) red[tid] = fmaxf(red[tid], red[tid + s]);
        __syncthreads();
    }
    mx = red[0]; __syncthreads();
    float sum = 0.f;
#pragma unroll
    for (int i = 0; i < 8; ++i) { loc[i] = expf(loc[i] - mx); sum += loc[i]; }
    red[tid] = sum; __syncthreads();
    for (int s = 128; s > 0; s >>= 1) {
        if (tid < s) red[tid] += red[tid + s];
        __syncthreads();
    }
    const float inv = 1.0f / red[0];
#pragma unroll
    for (int i = 0; i < 8; ++i) alphas[b * SEQ + tid + i * 256] = loc[i] * inv;
}

// ---- context[b][h] = sum_s alphas[b][s] * values[b][s][h] (s split 64-way, atomics) ----
__global__ __launch_bounds__(256) void context_k(const float* __restrict__ alphas,
                                                 const float* __restrict__ values,
                                                 float* __restrict__ context) {
    __shared__ float al[32];
    const int b = blockIdx.y;
    const int s0 = blockIdx.x * 32;
    const int tid = threadIdx.x;
    if (tid < 32) al[tid] = alphas[b * SEQ + s0 + tid];
    __syncthreads();
    const int col = tid * 4;
    float4 acc = {0.f, 0.f, 0.f, 0.f};
#pragma unroll 8
    for (int i = 0; i < 32; ++i) {
        const float a = al[i];
        const float4 v = *(const float4*)(values + (size_t)(b * SEQ + s0 + i) * HID + col);
        acc.x += a * v.x; acc.y += a * v.y; acc.z += a * v.z; acc.w += a * v.w;
    }
    float* cp = context + b * HID + col;
    atomicAdd(cp + 0, acc.x);
    atomicAdd(cp + 1, acc.y);
    atomicAdd(cp + 2, acc.z);
    atomicAdd(cp + 3, acc.w);
}

extern "C" void kernel_launch(void* const* d_in, const int* in_sizes, int n_in,
                              void* d_out, int out_size, void* d_ws, size_t ws_size,
                              hipStream_t stream) {
    const float* queries = (const float*)d_in[0];
    const float* keys    = (const float*)d_in[1];
    const float* values  = (const float*)d_in[2];
    const float* W1      = (const float*)d_in[3];
    const float* b1      = (const float*)d_in[4];
    const float* W2      = (const float*)d_in[5];
    // d_in[6] = b2: softmax is shift-invariant; b2 affects neither alphas nor context.

    float* out_ctx   = (float*)d_out;            // [16,1024]
    float* out_alpha = (float*)d_out + NB * HID; // [16,2048]

    char* ws = (char*)d_ws;
    float* scores = (float*)ws;                       // 131072 B (atomic target)
    float* qproj  = (float*)(ws + 131072);            // 65536 B (atomic target)
    short* w1t    = (short*)(ws + 196608);            // 2 MiB

    (void)hipMemsetAsync(ws, 0, 196608, stream);      // scores + qproj

    prep_all<<<32 + 1024, 256, 0, stream>>>(W1, queries, b1, w1t, qproj);

    score_gemm<<<2048, 256, 0, stream>>>(keys, w1t, qproj, W2, scores);

    softmax_k<<<NB, 256, 0, stream>>>(scores, out_alpha, out_ctx);
    context_k<<<dim3(64, NB), 256, 0, stream>>>(out_alpha, values, out_ctx);
}

// Round 5
// 372.683 us; speedup vs baseline: 1.7000x; 1.1045x over previous
//
#include <hip/hip_runtime.h>

#define HID 1024
#define SEQ 2048
#define NB  16

typedef __attribute__((ext_vector_type(8))) short bf16x8;
typedef __attribute__((ext_vector_type(4))) float f32x4;

static __device__ __forceinline__ short f2bf(float f) {
    union { float f; unsigned u; } v; v.f = f;
    unsigned u = v.u + 0x7fffu + ((v.u >> 16) & 1u);   // round-to-nearest-even
    return (short)(u >> 16);
}
// HW-packed fp32x2 -> bf16x2 via v_cvt_pk_bf16_f32 (no builtin on gfx950)
static __device__ __forceinline__ unsigned pk2h(float a, float b) {
    unsigned r;
    asm("v_cvt_pk_bf16_f32 %0, %1, %2" : "=v"(r) : "v"(a), "v"(b));
    return r;
}
// async global->LDS, 16B per lane. LDS dest = wave-uniform base + lane*16.
static __device__ __forceinline__ void glds16(const void* g, void* l) {
    __builtin_amdgcn_global_load_lds(
        (const __attribute__((address_space(1))) unsigned*)g,
        (__attribute__((address_space(3))) unsigned*)l, 16, 0, 0);
}

// ---- prep (no atomics):
//   [0,32)        qproj_part[fc][b][n] = (fc==0 ? b1 : 0) + sum_{f in chunk fc} q[b][f]*W1[f][n]
//   [32,1056)     w1t[n][k] = bf16(W1[H+k][n])
//   [1056,+nconv) keys fp32 -> bf16 (kbf), 8 elems/thread
__global__ __launch_bounds__(256) void prep_all(const float* __restrict__ W1,
                                                const float* __restrict__ queries,
                                                const float* __restrict__ b1,
                                                const float* __restrict__ keys,
                                                short* __restrict__ w1t,
                                                float* __restrict__ qproj_part,
                                                short* __restrict__ kbf,
                                                int nconv) {
    __shared__ float shmem[2048];          // 8 KB, aliased per section
    const int tid = threadIdx.x;
    int bw = blockIdx.x;

    if (bw < 32) {
        const int fc = bw >> 2, nc = bw & 3;
        const int f0 = fc * 128, n0 = nc * 256;
#pragma unroll
        for (int j = 0; j < 8; ++j) {
            const int idx = tid * 8 + j;
            const int b = idx >> 7, f = idx & 127;
            shmem[idx] = queries[b * HID + f0 + f];
        }
        __syncthreads();
        float acc[16];
        const float bv = (fc == 0) ? b1[n0 + tid] : 0.0f;
#pragma unroll
        for (int b = 0; b < 16; ++b) acc[b] = bv;
        for (int f = 0; f < 128; ++f) {
            const float w = W1[(size_t)(f0 + f) * HID + n0 + tid];
#pragma unroll
            for (int b = 0; b < 16; ++b)
                acc[b] += shmem[b * 128 + f] * w;
        }
#pragma unroll
        for (int b = 0; b < 16; ++b)
            qproj_part[(size_t)(fc * 16 + b) * HID + n0 + tid] = acc[b];   // direct store
        return;
    }
    bw -= 32;
    if (bw < 1024) {  // w1t transpose, 32x32 tiles
        float (*t)[33] = (float(*)[33])shmem;
        const int k0 = (bw & 31) * 32;
        const int n0 = (bw >> 5) * 32;
        const int tx = tid & 31, ty = tid >> 5;
#pragma unroll
        for (int i = 0; i < 32; i += 8)
            t[ty + i][tx] = W1[(size_t)(HID + k0 + ty + i) * HID + n0 + tx];
        __syncthreads();
#pragma unroll
        for (int i = 0; i < 32; i += 8)
            w1t[(size_t)(n0 + ty + i) * HID + k0 + tx] = f2bf(t[tx][ty + i]);
        return;
    }
    bw -= 1024;
    if (bw < nconv) {  // keys fp32 -> bf16
        const size_t i = ((size_t)bw * 256 + tid) * 8;
        const float4 a = *(const float4*)(keys + i);
        const float4 b = *(const float4*)(keys + i + 4);
        int4 o;
        o.x = (int)pk2h(a.x, a.y); o.y = (int)pk2h(a.z, a.w);
        o.z = (int)pk2h(b.x, b.y); o.w = (int)pk2h(b.z, b.w);
        *(int4*)(kbf + i) = o;
    }
}

// ---- main fused score GEMM: 128x128 tile, BK=32, 4 waves (2x2), 4x4 frags/wave.
// m97 structure: glds for BOTH operands, single-buffer, 2 barriers/iter — no
// in-loop VALU staging at all (16 MFMA + 8 ds_read + 4 glds per wave-iter).
//
// XCD sibling swizzle: 8 n-blocks sharing one A-panel -> same id%8 -> same XCD.
// LDS XOR swizzle (verified 0-conflict in r4): phys 16B-slot = s ^ ((row>>1)&3),
// applied by pre-permuting the glds SOURCE k-chunk per lane (LDS dest linear);
// reads use slot q ^ ((c>>1)&3).
//
// Epilogue: qv = sum of 8 qproj_part planes; relu(acc+qv)*W2; reduce over c
// lanes, then cross-wn pair through LDS; direct store to scores_part[n_blk].
template<int PRE>
__global__ __launch_bounds__(256, 4) void score_gemm(const float* __restrict__ keys,
                                                     const short* __restrict__ kbf,
                                                     const short* __restrict__ w1t,
                                                     const float* __restrict__ qproj_part,
                                                     const float* __restrict__ W2,
                                                     float* __restrict__ scores_part) {
    __shared__ short As[128 * 32];
    __shared__ short Bs[128 * 32];
    __shared__ float red[4][64];

    const int tid  = threadIdx.x;
    const int lane = tid & 63;
    const int wave = tid >> 6;
    const int id   = blockIdx.x;
    const int n_blk = (id >> 3) & 7;
    const int m_blk = (id >> 6) * 8 + (id & 7);
    const int n0 = n_blk * 128;
    const int m0 = m_blk * 128;
    const int batch = m0 >> 11;
    const int wm = wave >> 1, wn = wave & 1;
    const int q = lane >> 4, c = lane & 15;
    const int xr = (c >> 1) & 3;               // read-side XOR

    // glds source mapping (both operands): row = rbase + lane/4, source k-chunk
    // pre-permuted so the linear LDS dest receives phys = s ^ ((row>>1)&3).
    const int lrow = lane >> 2;
    const int lk   = ((lane & 3) ^ ((lane >> 3) & 3)) << 3;
    const short* bsrc = w1t + (size_t)(n0 + lrow) * HID + lk;
    const short* asrc = kbf + (size_t)(m0 + lrow) * HID + lk;

    // PRE=0 fallback staging map (in-loop cvt, swizzled ds_write)
    const int ar  = tid >> 1;
    const int ah  = (tid & 1) * 16;
    const int g_ar = (ar >> 1) & 3;
    const int as0 = (((ah >> 3) + 0) ^ g_ar) << 3;
    const int as1 = (((ah >> 3) + 1) ^ g_ar) << 3;
    const float* afsrc = keys + (size_t)(m0 + ar) * HID + ah;

    f32x4 acc[4][4] = {};

    for (int k0 = 0; k0 < HID; k0 += 32) {
#pragma unroll
        for (int call = 0; call < 2; ++call) {
            const int rbase = (wave * 2 + call) * 16;
            glds16(bsrc + (size_t)rbase * HID + k0, &Bs[rbase * 32]);
        }
        if (PRE) {
#pragma unroll
            for (int call = 0; call < 2; ++call) {
                const int rbase = (wave * 2 + call) * 16;
                glds16(asrc + (size_t)rbase * HID + k0, &As[rbase * 32]);
            }
        } else {
            const float4 v0 = *(const float4*)(afsrc + k0 + 0);
            const float4 v1 = *(const float4*)(afsrc + k0 + 4);
            const float4 v2 = *(const float4*)(afsrc + k0 + 8);
            const float4 v3 = *(const float4*)(afsrc + k0 + 12);
            int4 o0, o1;
            o0.x = (int)pk2h(v0.x, v0.y); o0.y = (int)pk2h(v0.z, v0.w);
            o0.z = (int)pk2h(v1.x, v1.y); o0.w = (int)pk2h(v1.z, v1.w);
            o1.x = (int)pk2h(v2.x, v2.y); o1.y = (int)pk2h(v2.z, v2.w);
            o1.z = (int)pk2h(v3.x, v3.y); o1.w = (int)pk2h(v3.z, v3.w);
            *(int4*)&As[ar * 32 + as0] = o0;
            *(int4*)&As[ar * 32 + as1] = o1;
        }
        __syncthreads();

        bf16x8 af[4], bf[4];
#pragma unroll
        for (int i = 0; i < 4; ++i)
            af[i] = *(const bf16x8*)&As[(wm * 64 + i * 16 + c) * 32 + ((q ^ xr) << 3)];
#pragma unroll
        for (int i = 0; i < 4; ++i)
            bf[i] = *(const bf16x8*)&Bs[(wn * 64 + i * 16 + c) * 32 + ((q ^ xr) << 3)];
#pragma unroll
        for (int mi = 0; mi < 4; ++mi)
#pragma unroll
            for (int ni = 0; ni < 4; ++ni)
                acc[mi][ni] = __builtin_amdgcn_mfma_f32_16x16x32_bf16(af[mi], bf[ni], acc[mi][ni], 0, 0, 0);
        __syncthreads();
    }

    // epilogue: relu(acc + qproj) * W2, reduce over this wave's 64 n-cols
    const float* w2 = W2 + n0 + wn * 64;
    float psum[4][4] = {};
#pragma unroll
    for (int ni = 0; ni < 4; ++ni) {
        const int n = n0 + wn * 64 + ni * 16 + c;
        float qv = 0.f;
#pragma unroll
        for (int p = 0; p < 8; ++p)
            qv += qproj_part[(size_t)(p * 16 + batch) * HID + n];
        const float wv = w2[ni * 16 + c];
#pragma unroll
        for (int mi = 0; mi < 4; ++mi)
#pragma unroll
            for (int r = 0; r < 4; ++r)
                psum[mi][r] += fmaxf(acc[mi][ni][r] + qv, 0.f) * wv;
    }
#pragma unroll
    for (int m = 1; m < 16; m <<= 1)
#pragma unroll
        for (int mi = 0; mi < 4; ++mi)
#pragma unroll
            for (int r = 0; r < 4; ++r)
                psum[mi][r] += __shfl_xor(psum[mi][r], m, 64);
    if (c == 0) {
#pragma unroll
        for (int mi = 0; mi < 4; ++mi)
#pragma unroll
            for (int r = 0; r < 4; ++r)
                red[wave][mi * 16 + q * 4 + r] = psum[mi][r];
    }
    __syncthreads();
    if (tid < 128) {   // sum wn pair, direct store (no atomics)
        const int wm2 = tid >> 6, idx = tid & 63;
        scores_part[(size_t)n_blk * (SEQ * NB) + m0 + wm2 * 64 + idx] =
            red[wm2 * 2][idx] + red[wm2 * 2 + 1][idx];
    }
}

// ---- softmax over S per batch: sums the 8 n_blk partial planes first ----
__global__ __launch_bounds__(256) void softmax_k(const float* __restrict__ scores_part,
                                                 float* __restrict__ alphas) {
    __shared__ float red[256];
    const int b = blockIdx.x;
    const int tid = threadIdx.x;
    const float* sp = scores_part + b * SEQ;

    float loc[8];
    float mx = -1e30f;
#pragma unroll
    for (int i = 0; i < 8; ++i) {
        const int s = tid + i * 256;
        float v = 0.f;
#pragma unroll
        for (int p = 0; p < 8; ++p)
            v += sp[(size_t)p * (SEQ * NB) + s];
        loc[i] = v;
        mx = fmaxf(mx, v);
    }
    red[tid] = mx; __syncthreads();
    for (int s = 128; s > 0; s >>= 1) {
        if (tid < s) red[tid] = fmaxf(red[tid], red[tid + s]);
        __syncthreads();
    }
    mx = red[0]; __syncthreads();
    float sum = 0.f;
#pragma unroll
    for (int i = 0; i < 8; ++i) { loc[i] = expf(loc[i] - mx); sum += loc[i]; }
    red[tid] = sum; __syncthreads();
    for (int s = 128; s > 0; s >>= 1) {
        if (tid < s) red[tid] += red[tid + s];
        __syncthreads();
    }
    const float inv = 1.0f / red[0];
#pragma unroll
    for (int i = 0; i < 8; ++i) alphas[b * SEQ + tid + i * 256] = loc[i] * inv;
}

// ---- context partials: block (sb,b) owns 64 s-values, writes ctx_part[sb][b][:] ----
__global__ __launch_bounds__(256) void context_part_k(const float* __restrict__ alphas,
                                                      const float* __restrict__ values,
                                                      float* __restrict__ ctx_part) {
    __shared__ float al[64];
    const int b = blockIdx.y;
    const int sb = blockIdx.x;           // 32 splits
    const int s0 = sb * 64;
    const int tid = threadIdx.x;
    if (tid < 64) al[tid] = alphas[b * SEQ + s0 + tid];
    __syncthreads();
    const int col = tid * 4;
    float4 acc = {0.f, 0.f, 0.f, 0.f};
#pragma unroll 8
    for (int i = 0; i < 64; ++i) {
        const float a = al[i];
        const float4 v = *(const float4*)(values + (size_t)(b * SEQ + s0 + i) * HID + col);
        acc.x += a * v.x; acc.y += a * v.y; acc.z += a * v.z; acc.w += a * v.w;
    }
    *(float4*)(ctx_part + (size_t)(sb * NB + b) * HID + col) = acc;
}

// ---- reduce 32 context partials -> out_ctx (no atomics) ----
__global__ __launch_bounds__(256) void ctx_reduce_k(const float* __restrict__ ctx_part,
                                                    float* __restrict__ context) {
    const int b = blockIdx.x;
    const int col = threadIdx.x * 4;
    float4 s = {0.f, 0.f, 0.f, 0.f};
#pragma unroll
    for (int p = 0; p < 32; ++p) {
        const float4 v = *(const float4*)(ctx_part + (size_t)(p * NB + b) * HID + col);
        s.x += v.x; s.y += v.y; s.z += v.z; s.w += v.w;
    }
    *(float4*)(context + b * HID + col) = s;
}

extern "C" void kernel_launch(void* const* d_in, const int* in_sizes, int n_in,
                              void* d_out, int out_size, void* d_ws, size_t ws_size,
                              hipStream_t stream) {
    const float* queries = (const float*)d_in[0];
    const float* keys    = (const float*)d_in[1];
    const float* values  = (const float*)d_in[2];
    const float* W1      = (const float*)d_in[3];
    const float* b1      = (const float*)d_in[4];
    const float* W2      = (const float*)d_in[5];
    // d_in[6] = b2: softmax is shift-invariant; b2 affects neither alphas nor context.

    float* out_ctx   = (float*)d_out;            // [16,1024]
    float* out_alpha = (float*)d_out + NB * HID; // [16,2048]

    char* ws = (char*)d_ws;
    float* scores_part = (float*)ws;                    // 8 x 32768 f32 = 1 MiB
    float* qproj_part  = (float*)(ws + 1048576);        // 8 x 16 x 1024 f32 = 512 KiB
    float* ctx_part    = (float*)(ws + 1572864);        // 32 x 16 x 1024 f32 = 2 MiB
    short* w1t         = (short*)(ws + 3670016);        // 2 MiB
    short* kbf         = (short*)(ws + 5767168);        // 64 MiB

    const bool pre = ws_size >= 72876032ull;
    const int nconv = pre ? 16384 : 0;

    prep_all<<<32 + 1024 + nconv, 256, 0, stream>>>(
        W1, queries, b1, keys, w1t, qproj_part, kbf, nconv);

    if (pre)
        score_gemm<1><<<2048, 256, 0, stream>>>(keys, kbf, w1t, qproj_part, W2, scores_part);
    else
        score_gemm<0><<<2048, 256, 0, stream>>>(keys, kbf, w1t, qproj_part, W2, scores_part);

    softmax_k<<<NB, 256, 0, stream>>>(scores_part, out_alpha);
    context_part_k<<<dim3(32, NB), 256, 0, stream>>>(out_alpha, values, ctx_part);
    ctx_reduce_k<<<NB, 256, 0, stream>>>(ctx_part, out_ctx);
}

// Round 6
// 368.978 us; speedup vs baseline: 1.7171x; 1.0100x over previous
//
#include <hip/hip_runtime.h>

#define HID 1024
#define SEQ 2048
#define NB  16

typedef __attribute__((ext_vector_type(8))) short bf16x8;
typedef __attribute__((ext_vector_type(4))) float f32x4;

static __device__ __forceinline__ short f2bf(float f) {
    union { float f; unsigned u; } v; v.f = f;
    unsigned u = v.u + 0x7fffu + ((v.u >> 16) & 1u);   // round-to-nearest-even
    return (short)(u >> 16);
}
// HW-packed fp32x2 -> bf16x2 via v_cvt_pk_bf16_f32 (no builtin on gfx950)
static __device__ __forceinline__ unsigned pk2h(float a, float b) {
    unsigned r;
    asm("v_cvt_pk_bf16_f32 %0, %1, %2" : "=v"(r) : "v"(a), "v"(b));
    return r;
}
// async global->LDS, 16B per lane. LDS dest = wave-uniform base + lane*16.
static __device__ __forceinline__ void glds16(const void* g, void* l) {
    __builtin_amdgcn_global_load_lds(
        (const __attribute__((address_space(1))) unsigned*)g,
        (__attribute__((address_space(3))) unsigned*)l, 16, 0, 0);
}

// ---- prep (no atomics):
//   [0,32)        qproj_part[fc][b][n] = (fc==0 ? b1 : 0) + sum_{f in chunk fc} q[b][f]*W1[f][n]
//   [32,1056)     w1t[n][k] = bf16(W1[H+k][n])
//   [1056,1072)   zero out_ctx (atomic target of tail_k)
//   [1072,+nconv) keys fp32 -> bf16 (kbf), 8 elems/thread
__global__ __launch_bounds__(256) void prep_all(const float* __restrict__ W1,
                                                const float* __restrict__ queries,
                                                const float* __restrict__ b1,
                                                const float* __restrict__ keys,
                                                short* __restrict__ w1t,
                                                float* __restrict__ qproj_part,
                                                short* __restrict__ kbf,
                                                float* __restrict__ out_ctx,
                                                int nconv) {
    __shared__ float shmem[2048];          // 8 KB, aliased per section
    const int tid = threadIdx.x;
    int bw = blockIdx.x;

    if (bw < 32) {
        const int fc = bw >> 2, nc = bw & 3;
        const int f0 = fc * 128, n0 = nc * 256;
#pragma unroll
        for (int j = 0; j < 8; ++j) {
            const int idx = tid * 8 + j;
            const int b = idx >> 7, f = idx & 127;
            shmem[idx] = queries[b * HID + f0 + f];
        }
        __syncthreads();
        float acc[16];
        const float bv = (fc == 0) ? b1[n0 + tid] : 0.0f;
#pragma unroll
        for (int b = 0; b < 16; ++b) acc[b] = bv;
        for (int f = 0; f < 128; ++f) {
            const float w = W1[(size_t)(f0 + f) * HID + n0 + tid];
#pragma unroll
            for (int b = 0; b < 16; ++b)
                acc[b] += shmem[b * 128 + f] * w;
        }
#pragma unroll
        for (int b = 0; b < 16; ++b)
            qproj_part[(size_t)(fc * 16 + b) * HID + n0 + tid] = acc[b];   // direct store
        return;
    }
    bw -= 32;
    if (bw < 1024) {  // w1t transpose, 32x32 tiles
        float (*t)[33] = (float(*)[33])shmem;
        const int k0 = (bw & 31) * 32;
        const int n0 = (bw >> 5) * 32;
        const int tx = tid & 31, ty = tid >> 5;
#pragma unroll
        for (int i = 0; i < 32; i += 8)
            t[ty + i][tx] = W1[(size_t)(HID + k0 + ty + i) * HID + n0 + tx];
        __syncthreads();
#pragma unroll
        for (int i = 0; i < 32; i += 8)
            w1t[(size_t)(n0 + ty + i) * HID + k0 + tx] = f2bf(t[tx][ty + i]);
        return;
    }
    bw -= 1024;
    if (bw < 16) {  // zero out_ctx [16][1024]
        float4 z = {0.f, 0.f, 0.f, 0.f};
        *(float4*)(out_ctx + (size_t)(bw * 256 + tid) * 4) = z;
        return;
    }
    bw -= 16;
    if (bw < nconv) {  // keys fp32 -> bf16
        const size_t i = ((size_t)bw * 256 + tid) * 8;
        const float4 a = *(const float4*)(keys + i);
        const float4 b = *(const float4*)(keys + i + 4);
        int4 o;
        o.x = (int)pk2h(a.x, a.y); o.y = (int)pk2h(a.z, a.w);
        o.z = (int)pk2h(b.x, b.y); o.w = (int)pk2h(b.z, b.w);
        *(int4*)(kbf + i) = o;
    }
}

// ---- main fused score GEMM: UNCHANGED from round 5 (87 µs, 0 conflicts).
// 128x128 tile, BK=32, 4 waves (2x2), 4x4 frags/wave; glds both operands,
// single-buffer, 2 barriers/iter. XCD sibling swizzle; source-XOR LDS swizzle.
template<int PRE>
__global__ __launch_bounds__(256, 4) void score_gemm(const float* __restrict__ keys,
                                                     const short* __restrict__ kbf,
                                                     const short* __restrict__ w1t,
                                                     const float* __restrict__ qproj_part,
                                                     const float* __restrict__ W2,
                                                     float* __restrict__ scores_part) {
    __shared__ short As[128 * 32];
    __shared__ short Bs[128 * 32];
    __shared__ float red[4][64];

    const int tid  = threadIdx.x;
    const int lane = tid & 63;
    const int wave = tid >> 6;
    const int id   = blockIdx.x;
    const int n_blk = (id >> 3) & 7;
    const int m_blk = (id >> 6) * 8 + (id & 7);
    const int n0 = n_blk * 128;
    const int m0 = m_blk * 128;
    const int batch = m0 >> 11;
    const int wm = wave >> 1, wn = wave & 1;
    const int q = lane >> 4, c = lane & 15;
    const int xr = (c >> 1) & 3;               // read-side XOR

    const int lrow = lane >> 2;
    const int lk   = ((lane & 3) ^ ((lane >> 3) & 3)) << 3;
    const short* bsrc = w1t + (size_t)(n0 + lrow) * HID + lk;
    const short* asrc = kbf + (size_t)(m0 + lrow) * HID + lk;

    // PRE=0 fallback staging map (in-loop cvt, swizzled ds_write)
    const int ar  = tid >> 1;
    const int ah  = (tid & 1) * 16;
    const int g_ar = (ar >> 1) & 3;
    const int as0 = (((ah >> 3) + 0) ^ g_ar) << 3;
    const int as1 = (((ah >> 3) + 1) ^ g_ar) << 3;
    const float* afsrc = keys + (size_t)(m0 + ar) * HID + ah;

    f32x4 acc[4][4] = {};

    for (int k0 = 0; k0 < HID; k0 += 32) {
#pragma unroll
        for (int call = 0; call < 2; ++call) {
            const int rbase = (wave * 2 + call) * 16;
            glds16(bsrc + (size_t)rbase * HID + k0, &Bs[rbase * 32]);
        }
        if (PRE) {
#pragma unroll
            for (int call = 0; call < 2; ++call) {
                const int rbase = (wave * 2 + call) * 16;
                glds16(asrc + (size_t)rbase * HID + k0, &As[rbase * 32]);
            }
        } else {
            const float4 v0 = *(const float4*)(afsrc + k0 + 0);
            const float4 v1 = *(const float4*)(afsrc + k0 + 4);
            const float4 v2 = *(const float4*)(afsrc + k0 + 8);
            const float4 v3 = *(const float4*)(afsrc + k0 + 12);
            int4 o0, o1;
            o0.x = (int)pk2h(v0.x, v0.y); o0.y = (int)pk2h(v0.z, v0.w);
            o0.z = (int)pk2h(v1.x, v1.y); o0.w = (int)pk2h(v1.z, v1.w);
            o1.x = (int)pk2h(v2.x, v2.y); o1.y = (int)pk2h(v2.z, v2.w);
            o1.z = (int)pk2h(v3.x, v3.y); o1.w = (int)pk2h(v3.z, v3.w);
            *(int4*)&As[ar * 32 + as0] = o0;
            *(int4*)&As[ar * 32 + as1] = o1;
        }
        __syncthreads();

        bf16x8 af[4], bf[4];
#pragma unroll
        for (int i = 0; i < 4; ++i)
            af[i] = *(const bf16x8*)&As[(wm * 64 + i * 16 + c) * 32 + ((q ^ xr) << 3)];
#pragma unroll
        for (int i = 0; i < 4; ++i)
            bf[i] = *(const bf16x8*)&Bs[(wn * 64 + i * 16 + c) * 32 + ((q ^ xr) << 3)];
#pragma unroll
        for (int mi = 0; mi < 4; ++mi)
#pragma unroll
            for (int ni = 0; ni < 4; ++ni)
                acc[mi][ni] = __builtin_amdgcn_mfma_f32_16x16x32_bf16(af[mi], bf[ni], acc[mi][ni], 0, 0, 0);
        __syncthreads();
    }

    // epilogue: relu(acc + qproj) * W2, reduce over this wave's 64 n-cols
    const float* w2 = W2 + n0 + wn * 64;
    float psum[4][4] = {};
#pragma unroll
    for (int ni = 0; ni < 4; ++ni) {
        const int n = n0 + wn * 64 + ni * 16 + c;
        float qv = 0.f;
#pragma unroll
        for (int p = 0; p < 8; ++p)
            qv += qproj_part[(size_t)(p * 16 + batch) * HID + n];
        const float wv = w2[ni * 16 + c];
#pragma unroll
        for (int mi = 0; mi < 4; ++mi)
#pragma unroll
            for (int r = 0; r < 4; ++r)
                psum[mi][r] += fmaxf(acc[mi][ni][r] + qv, 0.f) * wv;
    }
#pragma unroll
    for (int m = 1; m < 16; m <<= 1)
#pragma unroll
        for (int mi = 0; mi < 4; ++mi)
#pragma unroll
            for (int r = 0; r < 4; ++r)
                psum[mi][r] += __shfl_xor(psum[mi][r], m, 64);
    if (c == 0) {
#pragma unroll
        for (int mi = 0; mi < 4; ++mi)
#pragma unroll
            for (int r = 0; r < 4; ++r)
                red[wave][mi * 16 + q * 4 + r] = psum[mi][r];
    }
    __syncthreads();
    if (tid < 128) {   // sum wn pair, direct store (no atomics)
        const int wm2 = tid >> 6, idx = tid & 63;
        scores_part[(size_t)n_blk * (SEQ * NB) + m0 + wm2 * 64 + idx] =
            red[wm2 * 2][idx] + red[wm2 * 2 + 1][idx];
    }
}

// ---- fused tail: softmax + context partial + atomic reduce in ONE kernel.
// Block (sb, b) redundantly computes batch-b softmax stats (8 planes from L2),
// writes its own 64-wide alpha slice, then does the context partial for that
// slice with in-register alphas -> atomicAdd into pre-zeroed out_ctx.
// No grid sync, no extra dispatches.
__global__ __launch_bounds__(256) void tail_k(const float* __restrict__ scores_part,
                                              const float* __restrict__ values,
                                              float* __restrict__ alphas,
                                              float* __restrict__ out_ctx) {
    __shared__ float red[256];
    __shared__ float al[64];
    const int b   = blockIdx.y;
    const int sb  = blockIdx.x;          // 32 s-splits of 64
    const int s0  = sb * 64;
    const int tid = threadIdx.x;
    const float* sp = scores_part + b * SEQ;

    // full-row stats (redundant per sb — all L2-resident, 64 KB)
    float loc[8];
    float mx = -1e30f;
#pragma unroll
    for (int i = 0; i < 8; ++i) {
        const int s = tid + i * 256;
        float v = 0.f;
#pragma unroll
        for (int p = 0; p < 8; ++p)
            v += sp[(size_t)p * (SEQ * NB) + s];
        loc[i] = v;
        mx = fmaxf(mx, v);
    }
    red[tid] = mx; __syncthreads();
    for (int s = 128; s > 0; s >>= 1) {
        if (tid < s) red[tid] = fmaxf(red[tid], red[tid + s]);
        __syncthreads();
    }
    mx = red[0]; __syncthreads();
    float sum = 0.f;
#pragma unroll
    for (int i = 0; i < 8; ++i) sum += expf(loc[i] - mx);
    red[tid] = sum; __syncthreads();
    for (int s = 128; s > 0; s >>= 1) {
        if (tid < s) red[tid] += red[tid + s];
        __syncthreads();
    }
    const float inv = 1.0f / red[0];

    // this block's alpha slice [s0, s0+64)
    if (tid < 64) {
        float v = 0.f;
#pragma unroll
        for (int p = 0; p < 8; ++p)
            v += sp[(size_t)p * (SEQ * NB) + s0 + tid];
        const float a = expf(v - mx) * inv;
        al[tid] = a;
        alphas[b * SEQ + s0 + tid] = a;
    }
    __syncthreads();

    // context partial for this slice
    const int col = tid * 4;
    float4 acc = {0.f, 0.f, 0.f, 0.f};
#pragma unroll 8
    for (int i = 0; i < 64; ++i) {
        const float a = al[i];
        const float4 v = *(const float4*)(values + (size_t)(b * SEQ + s0 + i) * HID + col);
        acc.x += a * v.x; acc.y += a * v.y; acc.z += a * v.z; acc.w += a * v.w;
    }
    float* cp = out_ctx + b * HID + col;
    atomicAdd(cp + 0, acc.x);
    atomicAdd(cp + 1, acc.y);
    atomicAdd(cp + 2, acc.z);
    atomicAdd(cp + 3, acc.w);
}

extern "C" void kernel_launch(void* const* d_in, const int* in_sizes, int n_in,
                              void* d_out, int out_size, void* d_ws, size_t ws_size,
                              hipStream_t stream) {
    const float* queries = (const float*)d_in[0];
    const float* keys    = (const float*)d_in[1];
    const float* values  = (const float*)d_in[2];
    const float* W1      = (const float*)d_in[3];
    const float* b1      = (const float*)d_in[4];
    const float* W2      = (const float*)d_in[5];
    // d_in[6] = b2: softmax is shift-invariant; b2 affects neither alphas nor context.

    float* out_ctx   = (float*)d_out;            // [16,1024]
    float* out_alpha = (float*)d_out + NB * HID; // [16,2048]

    char* ws = (char*)d_ws;
    float* scores_part = (float*)ws;                    // 8 x 32768 f32 = 1 MiB
    float* qproj_part  = (float*)(ws + 1048576);        // 8 x 16 x 1024 f32 = 512 KiB
    short* w1t         = (short*)(ws + 1572864);        // 2 MiB
    short* kbf         = (short*)(ws + 3670016);        // 64 MiB

    const bool pre = ws_size >= 70778880ull;
    const int nconv = pre ? 16384 : 0;

    prep_all<<<32 + 1024 + 16 + nconv, 256, 0, stream>>>(
        W1, queries, b1, keys, w1t, qproj_part, kbf, out_ctx, nconv);

    if (pre)
        score_gemm<1><<<2048, 256, 0, stream>>>(keys, kbf, w1t, qproj_part, W2, scores_part);
    else
        score_gemm<0><<<2048, 256, 0, stream>>>(keys, kbf, w1t, qproj_part, W2, scores_part);

    tail_k<<<dim3(32, NB), 256, 0, stream>>>(scores_part, values, out_alpha, out_ctx);
}